// Round 5
// baseline (299.649 us; speedup 1.0000x reference)
//
#include <hip/hip_runtime.h>
#include <float.h>

#define B_ 8
#define S_ 1024
#define D_ 1024
#define H_ 16
#define HD_ 64

typedef __attribute__((ext_vector_type(8))) _Float16 half8;
typedef __attribute__((ext_vector_type(4))) _Float16 half4;
typedef __attribute__((ext_vector_type(4))) float f32x4;

__device__ __forceinline__ void gld16(const void* g, void* l) {
  __builtin_amdgcn_global_load_lds(
      (const __attribute__((address_space(1))) void*)g,
      (__attribute__((address_space(3))) void*)l, 16, 0, 0);
}

// ---------------------------------------------------------------- fused prep
// Grid: [0,768) cast_wqkv, [768,800) mask expand, [800,4896) cast_wo.
__global__ __launch_bounds__(256) void prep_kernel(
    const float* __restrict__ Wq, const float* __restrict__ bq,
    const float* __restrict__ Wk, const float* __restrict__ bk,
    const float* __restrict__ Wv, const float* __restrict__ bv,
    const float* __restrict__ Wo, const void* __restrict__ mraw,
    _Float16* __restrict__ Wc, float* __restrict__ bs,
    _Float16* __restrict__ Wo16, float* __restrict__ maskadd) {
  const int bid = blockIdx.x;
  const int tid = threadIdx.x;
  if (bid < 768) {
    const int idx = bid * 256 + tid;  // < 196608
    const int d = idx & 63;
    const int e = (idx >> 6) & 63;
    const int t2 = idx >> 12;
    const int m = t2 % 3, h = t2 / 3;
    const int src = h * 4096 + d * 64 + e;
    float v = (m == 0) ? Wq[src] * 0.18033688f : (m == 1) ? Wk[src] : Wv[src];
    Wc[idx] = (_Float16)v;
    if (idx < 3072) {
      const int mm = idx >> 10, he = idx & 1023;
      float vv = (mm == 0) ? bq[he] * 0.18033688f : (mm == 1) ? bk[he] : bv[he];
      bs[idx] = vv;
    }
  } else if (bid < 800) {
    __shared__ int bad;
    if (tid == 0) bad = 0;
    __syncthreads();
    const unsigned int* mw = (const unsigned int*)mraw;
    int my = 0;
    for (int j = tid; j < 2048; j += 256) my |= (mw[j] & ~1u) ? 1 : 0;
    if (my) atomicOr(&bad, 1);
    __syncthreads();
    const int i = (bid - 768) * 256 + tid;
    const int f = bad;  // 1 => byte layout
    const int v = f ? (int)((const unsigned char*)mraw)[i] : ((const int*)mraw)[i];
    maskadd[i] = (v != 0) ? -FLT_MAX : 0.0f;
  } else {
    const int i = (bid - 800) * 256 + tid;  // < 1048576
    Wo16[i] = (_Float16)Wo[i];
  }
}

// ---------------------------------------------------------------- fused QKV + flash attention
// qkv_kernel is gone: per chunk, each wave projects a 16-row x slab to K and V
// with MFMA and writes them into the SAME XOR-swizzled LDS layout the consume
// phase already reads (projection D-layout lands exactly on the swizzle; the
// consume code is byte-identical to R4's proven kernel). Q is projected once
// through a per-wave LDS bounce (D-layout -> operand-layout transpose).
// Biases ride in the MFMA C-operand. Removes 100 MB of q16/k16/vT16 traffic
// and one kernel launch for +33% MFMA in-kernel and 4x redundant K/V
// projection (x slabs are L2-served: all 4 qblk blocks of a bh share an XCD).
__global__ __launch_bounds__(256, 2) void attn_kernel(
    const float* __restrict__ x, const _Float16* __restrict__ Wc,
    const float* __restrict__ bs, const float* __restrict__ maskadd,
    _Float16* __restrict__ att) {
  __shared__ alignas(16) _Float16 Ks[2][64 * 64];
  __shared__ alignas(16) _Float16 Vs[2][64 * 64];
  __shared__ alignas(16) _Float16 Qstage[4 * 64 * 64];
  const int bh = blockIdx.x & 127;   // XCD swizzle: 4 q-blocks of a bh share XCD
  const int qblk = blockIdx.x >> 7;  // 0..3
  const int b = bh >> 4, h = bh & 15;
  const int wv = threadIdx.x >> 6;
  const int lane = threadIdx.x & 63;
  const int quad = lane >> 4, col = lane & 15;
  const int c7 = col & 7;
  const int q0 = qblk * 256 + wv * 64;

  const float* __restrict__ xb = x + (size_t)b * S_ * D_ + h * HD_;
  const float* __restrict__ mrow = maskadd + b * S_;
  const _Float16* wbase = Wc + (size_t)h * 3 * 4096;
  const f32x4 z4 = {0.f, 0.f, 0.f, 0.f};

  // persistent weight fragments + biases (bias = MFMA C-operand init)
  half8 WK[4][2], WV[4][2];
  f32x4 bK[4];
  f32x4 bV[4];
#pragma unroll
  for (int et = 0; et < 4; ++et) {
    const _Float16* wrk = wbase + 4096 + (et * 16 + col) * 64;
    WK[et][0] = *(const half8*)(wrk + quad * 8);
    WK[et][1] = *(const half8*)(wrk + 32 + quad * 8);
    const _Float16* wrv = wbase + 8192 + (et * 16 + col) * 64;
    WV[et][0] = *(const half8*)(wrv + quad * 8);
    WV[et][1] = *(const half8*)(wrv + 32 + quad * 8);
    bK[et] = *(const f32x4*)(bs + 1024 + h * 64 + et * 16 + quad * 4);
    const float bv_ = bs[2048 + h * 64 + et * 16 + col];
    bV[et] = (f32x4){bv_, bv_, bv_, bv_};
  }

  // ---- Q projection: MFMA -> per-wave LDS stage (swizzled) -> operand regs
  {
    _Float16* Qs = &Qstage[wv * 4096];
#pragma unroll
    for (int qt = 0; qt < 4; ++qt) {
      const float* xr = xb + (size_t)(q0 + qt * 16 + col) * D_;
      f32x4 a0 = *(const f32x4*)(xr + quad * 8);
      f32x4 a1 = *(const f32x4*)(xr + quad * 8 + 4);
      f32x4 a2 = *(const f32x4*)(xr + 32 + quad * 8);
      f32x4 a3 = *(const f32x4*)(xr + 32 + quad * 8 + 4);
      half8 X0, X1;
#pragma unroll
      for (int j = 0; j < 4; ++j) {
        X0[j] = (_Float16)a0[j]; X0[4 + j] = (_Float16)a1[j];
        X1[j] = (_Float16)a2[j]; X1[4 + j] = (_Float16)a3[j];
      }
#pragma unroll
      for (int et = 0; et < 4; ++et) {
        const _Float16* wrq = wbase + (et * 16 + col) * 64;
        half8 Q0 = *(const half8*)(wrq + quad * 8);
        half8 Q1 = *(const half8*)(wrq + 32 + quad * 8);
        f32x4 bb = *(const f32x4*)(bs + h * 64 + et * 16 + quad * 4);
        f32x4 c = __builtin_amdgcn_mfma_f32_16x16x32_f16(Q0, X0, bb, 0, 0, 0);
        c = __builtin_amdgcn_mfma_f32_16x16x32_f16(Q1, X1, c, 0, 0, 0);
        half4 o;
#pragma unroll
        for (int r = 0; r < 4; ++r) o[r] = (_Float16)c[r];
        const int sg = (et * 2 + (quad >> 1)) ^ c7;
        *(half4*)&Qs[(qt * 16 + col) * 64 + sg * 8 + (quad & 1) * 4] = o;
      }
    }
  }
  __syncthreads();
  half8 Qf[4][2];
#pragma unroll
  for (int qt = 0; qt < 4; ++qt) {
    const int rb = wv * 4096 + (qt * 16 + col) * 64;
    Qf[qt][0] = *(const half8*)&Qstage[rb + (quad ^ c7) * 8];
    Qf[qt][1] = *(const half8*)&Qstage[rb + ((4 + quad) ^ c7) * 8];
  }

  f32x4 O[4][4];
#pragma unroll
  for (int qt = 0; qt < 4; ++qt)
#pragma unroll
    for (int et = 0; et < 4; ++et) O[qt][et] = z4;
  float l[4] = {0.f, 0.f, 0.f, 0.f};

  // chunk projection: wave wv projects x rows c*64+wv*16+(0..15) to K and V
  auto project = [&](int c, int buf) {
    const float* xr = xb + (size_t)(c * 64 + wv * 16 + col) * D_;
    f32x4 a0 = *(const f32x4*)(xr + quad * 8);
    f32x4 a1 = *(const f32x4*)(xr + quad * 8 + 4);
    f32x4 a2 = *(const f32x4*)(xr + 32 + quad * 8);
    f32x4 a3 = *(const f32x4*)(xr + 32 + quad * 8 + 4);
    half8 X0, X1;
#pragma unroll
    for (int j = 0; j < 4; ++j) {
      X0[j] = (_Float16)a0[j]; X0[4 + j] = (_Float16)a1[j];
      X1[j] = (_Float16)a2[j]; X1[4 + j] = (_Float16)a3[j];
    }
    _Float16* KD = &Ks[buf][0];
    _Float16* VD = &Vs[buf][0];
#pragma unroll
    for (int et = 0; et < 4; ++et) {
      // K: D(key = wv*16+col, e = et*16+quad*4+r)
      f32x4 ck = __builtin_amdgcn_mfma_f32_16x16x32_f16(WK[et][0], X0, bK[et], 0, 0, 0);
      ck = __builtin_amdgcn_mfma_f32_16x16x32_f16(WK[et][1], X1, ck, 0, 0, 0);
      half4 ok;
#pragma unroll
      for (int r = 0; r < 4; ++r) ok[r] = (_Float16)ck[r];
      const int sgk = (et * 2 + (quad >> 1)) ^ c7;
      *(half4*)&KD[(wv * 16 + col) * 64 + sgk * 8 + (quad & 1) * 4] = ok;
      // V: D(e = et*16+col, key = wv*16+quad*4+r)
      f32x4 cv = __builtin_amdgcn_mfma_f32_16x16x32_f16(X0, WV[et][0], bV[et], 0, 0, 0);
      cv = __builtin_amdgcn_mfma_f32_16x16x32_f16(X1, WV[et][1], cv, 0, 0, 0);
      half4 ov;
#pragma unroll
      for (int r = 0; r < 4; ++r) ov[r] = (_Float16)cv[r];
      const int sgv = (wv * 2 + (quad >> 1)) ^ c7;
      *(half4*)&VD[(et * 16 + col) * 64 + sgv * 8 + (quad & 1) * 4] = ov;
    }
  };

  project(0, 0);
  __syncthreads();

  for (int c = 0; c < 16; ++c) {
    const _Float16* Kb_ = &Ks[c & 1][0];
    const _Float16* Vb_ = &Vs[c & 1][0];
    const int kk0 = c * 64;
    f32x4 mkv[4];
#pragma unroll
    for (int kt = 0; kt < 4; ++kt) mkv[kt] = *(const f32x4*)(mrow + kk0 + kt * 16 + quad * 4);
    half8 Kf[4][2];
#pragma unroll
    for (int kt = 0; kt < 4; ++kt) {
      const int rb = (kt * 16 + col) * 64;
      Kf[kt][0] = *(const half8*)&Kb_[rb + ((quad) ^ c7) * 8];
      Kf[kt][1] = *(const half8*)&Kb_[rb + ((4 + quad) ^ c7) * 8];
    }
    half4 Vf[4][4];
#pragma unroll
    for (int kt = 0; kt < 4; ++kt) {
      const int sb = ((kt * 2 + (quad >> 1)) ^ c7) * 8 + (quad & 1) * 4;
#pragma unroll
      for (int et = 0; et < 4; ++et) Vf[kt][et] = *(const half4*)&Vb_[(et * 16 + col) * 64 + sb];
    }
#pragma unroll
    for (int qt = 0; qt < 4; ++qt) {
      f32x4 st[4];
#pragma unroll
      for (int kt = 0; kt < 4; ++kt) {
        f32x4 s = __builtin_amdgcn_mfma_f32_16x16x32_f16(Kf[kt][0], Qf[qt][0], mkv[kt], 0, 0, 0);
        st[kt] = __builtin_amdgcn_mfma_f32_16x16x32_f16(Kf[kt][1], Qf[qt][1], s, 0, 0, 0);
      }
      float p[16];
#pragma unroll
      for (int kt = 0; kt < 4; ++kt)
#pragma unroll
        for (int r = 0; r < 4; ++r) p[kt * 4 + r] = __builtin_amdgcn_exp2f(st[kt][r]);
      float s01 = (p[0] + p[1]) + (p[2] + p[3]);
      float s23 = (p[4] + p[5]) + (p[6] + p[7]);
      float s45 = (p[8] + p[9]) + (p[10] + p[11]);
      float s67 = (p[12] + p[13]) + (p[14] + p[15]);
      l[qt] += (s01 + s23) + (s45 + s67);
      half4 ph[4];
#pragma unroll
      for (int kt = 0; kt < 4; ++kt)
#pragma unroll
        for (int r = 0; r < 4; ++r) ph[kt][r] = (_Float16)p[kt * 4 + r];
#pragma unroll
      for (int et = 0; et < 4; ++et) {
        f32x4 o = O[qt][et];
#pragma unroll
        for (int kt = 0; kt < 4; ++kt)
          o = __builtin_amdgcn_mfma_f32_16x16x16f16(Vf[kt][et], ph[kt], o, 0, 0, 0);
        O[qt][et] = o;
      }
    }
    if (c < 15) project(c + 1, (c + 1) & 1);
    __syncthreads();
  }

#pragma unroll
  for (int qt = 0; qt < 4; ++qt) {
    float lt = l[qt];
    lt += __shfl_xor(lt, 16);
    lt += __shfl_xor(lt, 32);
    const float inv = 1.0f / lt;
    _Float16* orow = att + ((size_t)(b * S_ + q0 + qt * 16 + col)) * D_ + h * HD_;
#pragma unroll
    for (int et = 0; et < 4; ++et) {
      half4 o;
#pragma unroll
      for (int r = 0; r < 4; ++r) o[r] = (_Float16)(O[qt][et][r] * inv);
      *(half4*)(orow + et * 16 + quad * 4) = o;
    }
  }
}

// ---------------------------------------------------------------- out projection, m97-style
// XCD-chunked bid remap: all 8 n-tiles of an m-tile on one XCD (A-panel L2-resident).
__global__ __launch_bounds__(256, 4) void outproj_kernel(
    const _Float16* __restrict__ A, const _Float16* __restrict__ Bw,
    const float* __restrict__ bo, float* __restrict__ C) {
  __shared__ alignas(16) _Float16 As[128 * 64];
  __shared__ alignas(16) _Float16 Bs[128 * 64];
  const int x_ = blockIdx.x & 7;
  const int t_ = blockIdx.x >> 3;
  const int n_ = t_ & 7;
  const int mlo = t_ >> 3;
  const int m0 = (x_ * 8 + mlo) * 128;
  const int n0 = n_ * 128;
  const int t = threadIdx.x;
  const int lane = t & 63, wv = t >> 6;
  const int quad = lane >> 4, col = lane & 15;
  const int mw = (wv >> 1) * 64, nw = (wv & 1) * 64;

  int rowS[4], segS[4];
#pragma unroll
  for (int sweep = 0; sweep < 4; ++sweep) {
    const int s = sweep * 256 + wv * 64 + lane;
    rowS[sweep] = s >> 3;
    segS[sweep] = (s & 7) ^ (rowS[sweep] & 7);
  }

  f32x4 acc[16];
  const f32x4 z4 = {0.f, 0.f, 0.f, 0.f};
#pragma unroll
  for (int i = 0; i < 16; ++i) acc[i] = z4;

  for (int kt = 0; kt < 16; ++kt) {
#pragma unroll
    for (int sweep = 0; sweep < 4; ++sweep) {
      const int ldsbase = (sweep * 256 + wv * 64) * 8;
      gld16(A + (size_t)(m0 + rowS[sweep]) * D_ + kt * 64 + segS[sweep] * 8, &As[ldsbase]);
      gld16(Bw + (size_t)(n0 + rowS[sweep]) * D_ + kt * 64 + segS[sweep] * 8, &Bs[ldsbase]);
    }
    __syncthreads();
#pragma unroll
    for (int ks = 0; ks < 2; ++ks) {
      half8 aF[4], bF[4];
#pragma unroll
      for (int mt = 0; mt < 4; ++mt) {
        const int row = mw + mt * 16 + col;
        aF[mt] = *(const half8*)&As[row * 64 + (((ks * 4 + quad) ^ (row & 7)) * 8)];
      }
#pragma unroll
      for (int nt = 0; nt < 4; ++nt) {
        const int row = nw + nt * 16 + col;
        bF[nt] = *(const half8*)&Bs[row * 64 + (((ks * 4 + quad) ^ (row & 7)) * 8)];
      }
#pragma unroll
      for (int mt = 0; mt < 4; ++mt)
#pragma unroll
        for (int nt = 0; nt < 4; ++nt)
          acc[mt * 4 + nt] =
              __builtin_amdgcn_mfma_f32_16x16x32_f16(aF[mt], bF[nt], acc[mt * 4 + nt], 0, 0, 0);
    }
    __syncthreads();
  }
#pragma unroll
  for (int mt = 0; mt < 4; ++mt)
#pragma unroll
    for (int nt = 0; nt < 4; ++nt) {
      f32x4 a = acc[mt * 4 + nt];
      const int n = n0 + nw + nt * 16 + col;
      const float bb = bo[n];
#pragma unroll
      for (int r = 0; r < 4; ++r) {
        const int mrow = m0 + mw + mt * 16 + quad * 4 + r;
        C[(size_t)mrow * D_ + n] = a[r] + bb;
      }
    }
}

// ---------------------------------------------------------------- launch
extern "C" void kernel_launch(void* const* d_in, const int* in_sizes, int n_in,
                              void* d_out, int out_size, void* d_ws, size_t ws_size,
                              hipStream_t stream) {
  const float* x  = (const float*)d_in[0];
  const float* Wq = (const float*)d_in[2];
  const float* bq = (const float*)d_in[3];
  const float* Wk = (const float*)d_in[4];
  const float* bk = (const float*)d_in[5];
  const float* Wv = (const float*)d_in[6];
  const float* bv = (const float*)d_in[7];
  const float* Wo = (const float*)d_in[8];
  const float* bo = (const float*)d_in[9];

  float* wsf     = (float*)d_ws;
  float* maskadd = wsf;                      // 8192 floats
  const size_t NE = (size_t)B_ * H_ * S_ * HD_;  // 8388608
  _Float16* hws  = (_Float16*)(wsf + 16384);
  _Float16* att16 = hws;                     // NE halves
  _Float16* Wo16 = att16 + NE;               // 1048576 halves
  _Float16* Wc   = Wo16 + 1048576;           // 196608 halves
  float*    bs   = (float*)(Wc + 196608);    // 3072 floats

  prep_kernel<<<4896, 256, 0, stream>>>(Wq, bq, Wk, bk, Wv, bv, Wo, d_in[1],
                                        Wc, bs, Wo16, maskadd);
  attn_kernel<<<B_ * H_ * (S_ / 256), 256, 0, stream>>>(x, Wc, bs, maskadd, att16);
  outproj_kernel<<<(B_ * S_ / 128) * (D_ / 128), 256, 0, stream>>>(att16, Wo16, bo, (float*)d_out);
}

// Round 6
// 201.383 us; speedup vs baseline: 1.4880x; 1.4880x over previous
//
#include <hip/hip_runtime.h>
#include <float.h>

#define B_ 8
#define S_ 1024
#define D_ 1024
#define H_ 16
#define HD_ 64

typedef __attribute__((ext_vector_type(8))) _Float16 half8;
typedef __attribute__((ext_vector_type(4))) _Float16 half4;
typedef __attribute__((ext_vector_type(4))) float f32x4;

__device__ __forceinline__ void gld16(const void* g, void* l) {
  __builtin_amdgcn_global_load_lds(
      (const __attribute__((address_space(1))) void*)g,
      (__attribute__((address_space(3))) void*)l, 16, 0, 0);
}

// ---------------------------------------------------------------- fused prep
// Grid: [0,768) cast_wqkv, [768,800) mask expand, [800,4896) cast_wo.
__global__ __launch_bounds__(256) void prep_kernel(
    const float* __restrict__ Wq, const float* __restrict__ bq,
    const float* __restrict__ Wk, const float* __restrict__ bk,
    const float* __restrict__ Wv, const float* __restrict__ bv,
    const float* __restrict__ Wo, const void* __restrict__ mraw,
    _Float16* __restrict__ Wc, float* __restrict__ bs,
    _Float16* __restrict__ Wo16, float* __restrict__ maskadd) {
  const int bid = blockIdx.x;
  const int tid = threadIdx.x;
  if (bid < 768) {
    const int idx = bid * 256 + tid;  // < 196608
    const int d = idx & 63;
    const int e = (idx >> 6) & 63;
    const int t2 = idx >> 12;
    const int m = t2 % 3, h = t2 / 3;
    const int src = h * 4096 + d * 64 + e;
    float v = (m == 0) ? Wq[src] * 0.18033688f : (m == 1) ? Wk[src] : Wv[src];
    Wc[idx] = (_Float16)v;
    if (idx < 3072) {
      const int mm = idx >> 10, he = idx & 1023;
      float vv = (mm == 0) ? bq[he] * 0.18033688f : (mm == 1) ? bk[he] : bv[he];
      bs[idx] = vv;
    }
  } else if (bid < 800) {
    __shared__ int bad;
    if (tid == 0) bad = 0;
    __syncthreads();
    const unsigned int* mw = (const unsigned int*)mraw;
    int my = 0;
    for (int j = tid; j < 2048; j += 256) my |= (mw[j] & ~1u) ? 1 : 0;
    if (my) atomicOr(&bad, 1);
    __syncthreads();
    const int i = (bid - 768) * 256 + tid;
    const int f = bad;  // 1 => byte layout
    const int v = f ? (int)((const unsigned char*)mraw)[i] : ((const int*)mraw)[i];
    maskadd[i] = (v != 0) ? -FLT_MAX : 0.0f;
  } else {
    const int i = (bid - 800) * 256 + tid;  // < 1048576
    Wo16[i] = (_Float16)Wo[i];
  }
}

// ---------------------------------------------------------------- QKV projection, row-coalesced
// One block = 16 FULL rows of x (all 16 heads). x is read with perfect
// row-major coalescing (one 4KB row per block-sweep -> ideal DRAM page
// locality; the old per-head kernel gathered 256B per 4KB row, ~1/16 page
// use). Staged f32->f16 in LDS with attn's proven XOR swizzle
// (byte ^= (row&7)<<4); each wave then computes 4 heads x {Q,K,V} via MFMA,
// bias in the C-operand (validated R5). Output layouts byte-identical to R4.
__global__ __launch_bounds__(256) void qkv_kernel(
    const float* __restrict__ x, const _Float16* __restrict__ Wc,
    const float* __restrict__ bs,
    _Float16* __restrict__ q16, _Float16* __restrict__ k16, _Float16* __restrict__ vT16) {
  __shared__ alignas(16) _Float16 Xs[16 * 1024];  // 32 KB, swizzled
  const int b = blockIdx.x >> 6;
  const int s0 = (blockIdx.x & 63) * 16;
  const int t = threadIdx.x;
  const int lane = t & 63, wv = t >> 6;
  const int col = lane & 15, quad = lane >> 4;

  // stage: one full 4KB row per sweep, 256 threads x f32x4 = 1024 floats
  for (int j = 0; j < 16; ++j) {
    f32x4 v = *(const f32x4*)(x + ((size_t)(b * S_) + s0 + j) * D_ + t * 4);
    half4 hv;
#pragma unroll
    for (int r = 0; r < 4; ++r) hv[r] = (_Float16)v[r];
    const int byte = (t * 8) ^ ((j & 7) << 4);
    *(half4*)((char*)&Xs[j * 1024] + byte) = hv;
  }
  __syncthreads();

  const f32x4 z4 = {0.f, 0.f, 0.f, 0.f};
  // X fragments: row = col (B-operand n-index = s-row), k-slices quad*8 (+32)
  const char* rp = (const char*)&Xs[col * 1024];
  const int xsw = (col & 7) << 4;

#pragma unroll
  for (int hi = 0; hi < 4; ++hi) {
    const int h = wv * 4 + hi;
    const int bh = (b << 4) | h;
    const _Float16* wbase = Wc + (size_t)h * 3 * 4096;
    half8 Xf0 = *(const half8*)(rp + ((h * 128 + quad * 16) ^ xsw));
    half8 Xf1 = *(const half8*)(rp + ((h * 128 + 64 + quad * 16) ^ xsw));
#pragma unroll
    for (int mm = 0; mm < 2; ++mm) {
      _Float16* outp = mm ? k16 : q16;
      const _Float16* wm = wbase + mm * 4096;
#pragma unroll
      for (int et = 0; et < 4; ++et) {
        const _Float16* wr = wm + (et * 16 + col) * 64;
        half8 W0 = *(const half8*)(wr + quad * 8);
        half8 W1 = *(const half8*)(wr + 32 + quad * 8);
        f32x4 bb = *(const f32x4*)(bs + mm * 1024 + h * 64 + et * 16 + quad * 4);
        f32x4 c = __builtin_amdgcn_mfma_f32_16x16x32_f16(W0, Xf0, bb, 0, 0, 0);
        c = __builtin_amdgcn_mfma_f32_16x16x32_f16(W1, Xf1, c, 0, 0, 0);
        half4 o;
#pragma unroll
        for (int r = 0; r < 4; ++r) o[r] = (_Float16)c[r];
        *(half4*)(outp + ((size_t)bh * S_ + s0 + col) * HD_ + et * 16 + quad * 4) = o;
      }
    }
    {
      const _Float16* wm = wbase + 2 * 4096;
#pragma unroll
      for (int et = 0; et < 4; ++et) {
        const _Float16* wr = wm + (et * 16 + col) * 64;
        half8 W0 = *(const half8*)(wr + quad * 8);
        half8 W1 = *(const half8*)(wr + 32 + quad * 8);
        const float bv_ = bs[2048 + h * 64 + et * 16 + col];
        const f32x4 bb = {bv_, bv_, bv_, bv_};
        f32x4 c = __builtin_amdgcn_mfma_f32_16x16x32_f16(Xf0, W0, bb, 0, 0, 0);
        c = __builtin_amdgcn_mfma_f32_16x16x32_f16(Xf1, W1, c, 0, 0, 0);
        half4 o;
#pragma unroll
        for (int r = 0; r < 4; ++r) o[r] = (_Float16)c[r];
        *(half4*)(vT16 + ((size_t)bh * HD_ + et * 16 + col) * S_ + s0 + quad * 4) = o;
      }
    }
  }
}

// ---------------------------------------------------------------- flash attention (R4-proven, unchanged)
__global__ __launch_bounds__(256, 2) void attn_kernel(
    const _Float16* __restrict__ q, const _Float16* __restrict__ k,
    const _Float16* __restrict__ vT, const float* __restrict__ maskadd,
    _Float16* __restrict__ att) {
  __shared__ alignas(16) _Float16 Ks[2][64 * 64];
  __shared__ alignas(16) _Float16 Vs[2][64 * 64];
  const int bh = blockIdx.x & 127;   // XCD swizzle: 4 q-blocks of a bh share XCD
  const int qblk = blockIdx.x >> 7;  // 0..3
  const int b = bh >> 4, h = bh & 15;
  const int wv = threadIdx.x >> 6;
  const int lane = threadIdx.x & 63;
  const int quad = lane >> 4, col = lane & 15;
  const int c7 = col & 7;
  const int q0 = qblk * 256 + wv * 64;

  const _Float16* __restrict__ kb = k + (size_t)bh * S_ * HD_;
  const _Float16* __restrict__ vb = vT + (size_t)bh * HD_ * S_;
  const float* __restrict__ mrow = maskadd + b * S_;

  const int jj0 = wv * 128 + lane, jj1 = jj0 + 64;
  const int r0s = jj0 >> 3, r1s = jj1 >> 3;
  const int sg0 = (jj0 & 7) ^ (r0s & 7), sg1 = (jj1 & 7) ^ (r1s & 7);
  const int offK0 = r0s * 128 + sg0 * 16, offK1 = r1s * 128 + sg1 * 16;
  const int offV0 = r0s * 2048 + sg0 * 16, offV1 = r1s * 2048 + sg1 * 16;
  const int ldsb0 = wv * 1024, ldsb1 = wv * 1024 + 512;

  half8 Qf[4][2];
#pragma unroll
  for (int qt = 0; qt < 4; ++qt) {
    const _Float16* qrow = q + ((size_t)bh * S_ + q0 + qt * 16 + col) * HD_;
    Qf[qt][0] = *(const half8*)(qrow + quad * 8);
    Qf[qt][1] = *(const half8*)(qrow + 32 + quad * 8);
  }

  const f32x4 z4 = {0.f, 0.f, 0.f, 0.f};
  f32x4 O[4][4];
#pragma unroll
  for (int qt = 0; qt < 4; ++qt)
#pragma unroll
    for (int et = 0; et < 4; ++et) O[qt][et] = z4;
  float l[4] = {0.f, 0.f, 0.f, 0.f};

  {
    const char* kg = (const char*)kb;
    const char* vg = (const char*)vb;
    gld16(kg + offK0, &Ks[0][ldsb0]);
    gld16(kg + offK1, &Ks[0][ldsb1]);
    gld16(vg + offV0, &Vs[0][ldsb0]);
    gld16(vg + offV1, &Vs[0][ldsb1]);
  }
  int cur = 0;
  for (int c = 0; c < 16; ++c) {
    __syncthreads();
    if (c < 15) {
      const char* kg = (const char*)kb + (size_t)(c + 1) * 8192;
      const char* vg = (const char*)vb + (size_t)(c + 1) * 128;
      gld16(kg + offK0, &Ks[cur ^ 1][ldsb0]);
      gld16(kg + offK1, &Ks[cur ^ 1][ldsb1]);
      gld16(vg + offV0, &Vs[cur ^ 1][ldsb0]);
      gld16(vg + offV1, &Vs[cur ^ 1][ldsb1]);
    }
    const int kk0 = c * 64;
    const _Float16* Kb_ = &Ks[cur][0];
    const _Float16* Vb_ = &Vs[cur][0];
    f32x4 mkv[4];
#pragma unroll
    for (int kt = 0; kt < 4; ++kt) mkv[kt] = *(const f32x4*)(mrow + kk0 + kt * 16 + quad * 4);
    half8 Kf[4][2];
#pragma unroll
    for (int kt = 0; kt < 4; ++kt) {
      const int rb = (kt * 16 + col) * 64;
      Kf[kt][0] = *(const half8*)&Kb_[rb + ((quad) ^ c7) * 8];
      Kf[kt][1] = *(const half8*)&Kb_[rb + ((4 + quad) ^ c7) * 8];
    }
    half4 Vf[4][4];
#pragma unroll
    for (int kt = 0; kt < 4; ++kt) {
      const int sb = ((kt * 2 + (quad >> 1)) ^ c7) * 8 + (quad & 1) * 4;
#pragma unroll
      for (int et = 0; et < 4; ++et) Vf[kt][et] = *(const half4*)&Vb_[(et * 16 + col) * 64 + sb];
    }
#pragma unroll
    for (int qt = 0; qt < 4; ++qt) {
      f32x4 st[4];
#pragma unroll
      for (int kt = 0; kt < 4; ++kt) {
        f32x4 s = __builtin_amdgcn_mfma_f32_16x16x32_f16(Kf[kt][0], Qf[qt][0], mkv[kt], 0, 0, 0);
        st[kt] = __builtin_amdgcn_mfma_f32_16x16x32_f16(Kf[kt][1], Qf[qt][1], s, 0, 0, 0);
      }
      float p[16];
#pragma unroll
      for (int kt = 0; kt < 4; ++kt)
#pragma unroll
        for (int r = 0; r < 4; ++r) p[kt * 4 + r] = __builtin_amdgcn_exp2f(st[kt][r]);
      float s01 = (p[0] + p[1]) + (p[2] + p[3]);
      float s23 = (p[4] + p[5]) + (p[6] + p[7]);
      float s45 = (p[8] + p[9]) + (p[10] + p[11]);
      float s67 = (p[12] + p[13]) + (p[14] + p[15]);
      l[qt] += (s01 + s23) + (s45 + s67);
      half4 ph[4];
#pragma unroll
      for (int kt = 0; kt < 4; ++kt)
#pragma unroll
        for (int r = 0; r < 4; ++r) ph[kt][r] = (_Float16)p[kt * 4 + r];
#pragma unroll
      for (int et = 0; et < 4; ++et) {
        f32x4 o = O[qt][et];
#pragma unroll
        for (int kt = 0; kt < 4; ++kt)
          o = __builtin_amdgcn_mfma_f32_16x16x16f16(Vf[kt][et], ph[kt], o, 0, 0, 0);
        O[qt][et] = o;
      }
    }
    cur ^= 1;
  }
#pragma unroll
  for (int qt = 0; qt < 4; ++qt) {
    float lt = l[qt];
    lt += __shfl_xor(lt, 16);
    lt += __shfl_xor(lt, 32);
    const float inv = 1.0f / lt;
    _Float16* orow = att + ((size_t)(b * S_ + q0 + qt * 16 + col)) * D_ + h * HD_;
#pragma unroll
    for (int et = 0; et < 4; ++et) {
      half4 o;
#pragma unroll
      for (int r = 0; r < 4; ++r) o[r] = (_Float16)(O[qt][et][r] * inv);
      *(half4*)(orow + et * 16 + quad * 4) = o;
    }
  }
}

// ---------------------------------------------------------------- out projection, m97-style (R4 unchanged)
__global__ __launch_bounds__(256, 4) void outproj_kernel(
    const _Float16* __restrict__ A, const _Float16* __restrict__ Bw,
    const float* __restrict__ bo, float* __restrict__ C) {
  __shared__ alignas(16) _Float16 As[128 * 64];
  __shared__ alignas(16) _Float16 Bs[128 * 64];
  const int x_ = blockIdx.x & 7;
  const int t_ = blockIdx.x >> 3;
  const int n_ = t_ & 7;
  const int mlo = t_ >> 3;
  const int m0 = (x_ * 8 + mlo) * 128;
  const int n0 = n_ * 128;
  const int t = threadIdx.x;
  const int lane = t & 63, wv = t >> 6;
  const int quad = lane >> 4, col = lane & 15;
  const int mw = (wv >> 1) * 64, nw = (wv & 1) * 64;

  int rowS[4], segS[4];
#pragma unroll
  for (int sweep = 0; sweep < 4; ++sweep) {
    const int s = sweep * 256 + wv * 64 + lane;
    rowS[sweep] = s >> 3;
    segS[sweep] = (s & 7) ^ (rowS[sweep] & 7);
  }

  f32x4 acc[16];
  const f32x4 z4 = {0.f, 0.f, 0.f, 0.f};
#pragma unroll
  for (int i = 0; i < 16; ++i) acc[i] = z4;

  for (int kt = 0; kt < 16; ++kt) {
#pragma unroll
    for (int sweep = 0; sweep < 4; ++sweep) {
      const int ldsbase = (sweep * 256 + wv * 64) * 8;
      gld16(A + (size_t)(m0 + rowS[sweep]) * D_ + kt * 64 + segS[sweep] * 8, &As[ldsbase]);
      gld16(Bw + (size_t)(n0 + rowS[sweep]) * D_ + kt * 64 + segS[sweep] * 8, &Bs[ldsbase]);
    }
    __syncthreads();
#pragma unroll
    for (int ks = 0; ks < 2; ++ks) {
      half8 aF[4], bF[4];
#pragma unroll
      for (int mt = 0; mt < 4; ++mt) {
        const int row = mw + mt * 16 + col;
        aF[mt] = *(const half8*)&As[row * 64 + (((ks * 4 + quad) ^ (row & 7)) * 8)];
      }
#pragma unroll
      for (int nt = 0; nt < 4; ++nt) {
        const int row = nw + nt * 16 + col;
        bF[nt] = *(const half8*)&Bs[row * 64 + (((ks * 4 + quad) ^ (row & 7)) * 8)];
      }
#pragma unroll
      for (int mt = 0; mt < 4; ++mt)
#pragma unroll
        for (int nt = 0; nt < 4; ++nt)
          acc[mt * 4 + nt] =
              __builtin_amdgcn_mfma_f32_16x16x32_f16(aF[mt], bF[nt], acc[mt * 4 + nt], 0, 0, 0);
    }
    __syncthreads();
  }
#pragma unroll
  for (int mt = 0; mt < 4; ++mt)
#pragma unroll
    for (int nt = 0; nt < 4; ++nt) {
      f32x4 a = acc[mt * 4 + nt];
      const int n = n0 + nw + nt * 16 + col;
      const float bb = bo[n];
#pragma unroll
      for (int r = 0; r < 4; ++r) {
        const int mrow = m0 + mw + mt * 16 + quad * 4 + r;
        C[(size_t)mrow * D_ + n] = a[r] + bb;
      }
    }
}

// ---------------------------------------------------------------- launch
extern "C" void kernel_launch(void* const* d_in, const int* in_sizes, int n_in,
                              void* d_out, int out_size, void* d_ws, size_t ws_size,
                              hipStream_t stream) {
  const float* x  = (const float*)d_in[0];
  const float* Wq = (const float*)d_in[2];
  const float* bq = (const float*)d_in[3];
  const float* Wk = (const float*)d_in[4];
  const float* bk = (const float*)d_in[5];
  const float* Wv = (const float*)d_in[6];
  const float* bv = (const float*)d_in[7];
  const float* Wo = (const float*)d_in[8];
  const float* bo = (const float*)d_in[9];

  float* wsf     = (float*)d_ws;
  float* maskadd = wsf;                      // 8192 floats
  const size_t NE = (size_t)B_ * H_ * S_ * HD_;  // 8388608
  _Float16* hws  = (_Float16*)(wsf + 16384);
  _Float16* q16  = hws;
  _Float16* k16  = q16 + NE;
  _Float16* vT16 = k16 + NE;
  _Float16* att16 = vT16 + NE;
  _Float16* Wo16 = att16 + NE;               // 1048576 halves
  _Float16* Wc   = Wo16 + 1048576;           // 196608 halves
  float*    bs   = (float*)(Wc + 196608);    // 3072 floats

  prep_kernel<<<4896, 256, 0, stream>>>(Wq, bq, Wk, bk, Wv, bv, Wo, d_in[1],
                                        Wc, bs, Wo16, maskadd);
  qkv_kernel<<<B_ * (S_ / 16), 256, 0, stream>>>(x, Wc, bs, q16, k16, vT16);
  attn_kernel<<<B_ * H_ * (S_ / 256), 256, 0, stream>>>(q16, k16, vT16, maskadd, att16);
  outproj_kernel<<<(B_ * S_ / 128) * (D_ / 128), 256, 0, stream>>>(att16, Wo16, bo, (float*)d_out);
}

// Round 8
// 190.201 us; speedup vs baseline: 1.5754x; 1.0588x over previous
//
#include <hip/hip_runtime.h>
#include <float.h>

#define B_ 8
#define S_ 1024
#define D_ 1024
#define H_ 16
#define HD_ 64

typedef __attribute__((ext_vector_type(8))) _Float16 half8;
typedef __attribute__((ext_vector_type(4))) _Float16 half4;
typedef __attribute__((ext_vector_type(4))) float f32x4;

__device__ __forceinline__ void gld16(const void* g, void* l) {
  __builtin_amdgcn_global_load_lds(
      (const __attribute__((address_space(1))) void*)g,
      (__attribute__((address_space(3))) void*)l, 16, 0, 0);
}

// ---------------------------------------------------------------- fused prep
// Grid: [0,768) cast_wqkv, [768,800) mask expand, [800,4896) cast_wo.
__global__ __launch_bounds__(256) void prep_kernel(
    const float* __restrict__ Wq, const float* __restrict__ bq,
    const float* __restrict__ Wk, const float* __restrict__ bk,
    const float* __restrict__ Wv, const float* __restrict__ bv,
    const float* __restrict__ Wo, const void* __restrict__ mraw,
    _Float16* __restrict__ Wc, float* __restrict__ bs,
    _Float16* __restrict__ Wo16, float* __restrict__ maskadd) {
  const int bid = blockIdx.x;
  const int tid = threadIdx.x;
  if (bid < 768) {
    const int idx = bid * 256 + tid;  // < 196608
    const int d = idx & 63;
    const int e = (idx >> 6) & 63;
    const int t2 = idx >> 12;
    const int m = t2 % 3, h = t2 / 3;
    const int src = h * 4096 + d * 64 + e;
    float v = (m == 0) ? Wq[src] * 0.18033688f : (m == 1) ? Wk[src] : Wv[src];
    Wc[idx] = (_Float16)v;
    if (idx < 3072) {
      const int mm = idx >> 10, he = idx & 1023;
      float vv = (mm == 0) ? bq[he] * 0.18033688f : (mm == 1) ? bk[he] : bv[he];
      bs[idx] = vv;
    }
  } else if (bid < 800) {
    __shared__ int bad;
    if (tid == 0) bad = 0;
    __syncthreads();
    const unsigned int* mw = (const unsigned int*)mraw;
    int my = 0;
    for (int j = tid; j < 2048; j += 256) my |= (mw[j] & ~1u) ? 1 : 0;
    if (my) atomicOr(&bad, 1);
    __syncthreads();
    const int i = (bid - 768) * 256 + tid;
    const int f = bad;  // 1 => byte layout
    const int v = f ? (int)((const unsigned char*)mraw)[i] : ((const int*)mraw)[i];
    maskadd[i] = (v != 0) ? -FLT_MAX : 0.0f;
  } else {
    const int i = (bid - 800) * 256 + tid;  // < 1048576
    Wo16[i] = (_Float16)Wo[i];
  }
}

// ---------------------------------------------------------------- QKV projection (R4-proven)
// 128 rows per block (2 row-tiles): weight fragments loaded once, used for
// both tiles. R6's row-coalesced variant regressed (-12us: 8x weight traffic,
// serial staging); this is the best measured structure.
__global__ __launch_bounds__(256) void qkv_kernel(
    const float* __restrict__ x, const _Float16* __restrict__ Wc,
    const float* __restrict__ bs,
    _Float16* __restrict__ q16, _Float16* __restrict__ k16, _Float16* __restrict__ vT16) {
  const int tp = blockIdx.x & 7;    // tile pair: rows s0..s0+127
  const int bh = blockIdx.x >> 3;
  const int b = bh >> 4, h = bh & 15;
  const int s0 = tp * 128;
  const int w = threadIdx.x >> 6, lane = threadIdx.x & 63;
  const int col = lane & 15, quad = lane >> 4;
  const int srowA = s0 + w * 16 + col;   // tile A row
  const int srowB = srowA + 64;          // tile B row

  half8 XA0, XA1, XB0, XB1;
  {
    const float* xrA = x + ((size_t)(b * S_) + srowA) * D_ + h * HD_;
    const float* xrB = x + ((size_t)(b * S_) + srowB) * D_ + h * HD_;
    f32x4 a0 = *(const f32x4*)(xrA + quad * 8);
    f32x4 a1 = *(const f32x4*)(xrA + quad * 8 + 4);
    f32x4 a2 = *(const f32x4*)(xrA + 32 + quad * 8);
    f32x4 a3 = *(const f32x4*)(xrA + 32 + quad * 8 + 4);
    f32x4 b0 = *(const f32x4*)(xrB + quad * 8);
    f32x4 b1 = *(const f32x4*)(xrB + quad * 8 + 4);
    f32x4 b2 = *(const f32x4*)(xrB + 32 + quad * 8);
    f32x4 b3 = *(const f32x4*)(xrB + 32 + quad * 8 + 4);
#pragma unroll
    for (int j = 0; j < 4; ++j) {
      XA0[j] = (_Float16)a0[j]; XA0[4 + j] = (_Float16)a1[j];
      XA1[j] = (_Float16)a2[j]; XA1[4 + j] = (_Float16)a3[j];
      XB0[j] = (_Float16)b0[j]; XB0[4 + j] = (_Float16)b1[j];
      XB1[j] = (_Float16)b2[j]; XB1[4 + j] = (_Float16)b3[j];
    }
  }

  const _Float16* wbase = Wc + (size_t)h * 3 * 4096;
  const f32x4 z4 = {0.f, 0.f, 0.f, 0.f};
#pragma unroll
  for (int mm = 0; mm < 2; ++mm) {
    _Float16* outp = mm ? k16 : q16;
    const _Float16* wm = wbase + mm * 4096;
#pragma unroll
    for (int et = 0; et < 4; ++et) {
      const _Float16* wr = wm + (et * 16 + col) * 64;
      half8 W0 = *(const half8*)(wr + quad * 8);
      half8 W1 = *(const half8*)(wr + 32 + quad * 8);
      f32x4 bb = *(const f32x4*)(bs + mm * 1024 + h * 64 + et * 16 + quad * 4);
      f32x4 cA = __builtin_amdgcn_mfma_f32_16x16x32_f16(W0, XA0, z4, 0, 0, 0);
      cA = __builtin_amdgcn_mfma_f32_16x16x32_f16(W1, XA1, cA, 0, 0, 0);
      f32x4 cB = __builtin_amdgcn_mfma_f32_16x16x32_f16(W0, XB0, z4, 0, 0, 0);
      cB = __builtin_amdgcn_mfma_f32_16x16x32_f16(W1, XB1, cB, 0, 0, 0);
      half4 oA, oB;
#pragma unroll
      for (int r = 0; r < 4; ++r) {
        oA[r] = (_Float16)(cA[r] + bb[r]);
        oB[r] = (_Float16)(cB[r] + bb[r]);
      }
      *(half4*)(outp + ((size_t)bh * S_ + srowA) * HD_ + et * 16 + quad * 4) = oA;
      *(half4*)(outp + ((size_t)bh * S_ + srowB) * HD_ + et * 16 + quad * 4) = oB;
    }
  }
  {
    const _Float16* wm = wbase + 2 * 4096;
#pragma unroll
    for (int et = 0; et < 4; ++et) {
      const _Float16* wr = wm + (et * 16 + col) * 64;
      half8 W0 = *(const half8*)(wr + quad * 8);
      half8 W1 = *(const half8*)(wr + 32 + quad * 8);
      float bb = bs[2048 + h * 64 + et * 16 + col];
      f32x4 cA = __builtin_amdgcn_mfma_f32_16x16x32_f16(XA0, W0, z4, 0, 0, 0);
      cA = __builtin_amdgcn_mfma_f32_16x16x32_f16(XA1, W1, cA, 0, 0, 0);
      f32x4 cB = __builtin_amdgcn_mfma_f32_16x16x32_f16(XB0, W0, z4, 0, 0, 0);
      cB = __builtin_amdgcn_mfma_f32_16x16x32_f16(XB1, W1, cB, 0, 0, 0);
      half4 oA, oB;
#pragma unroll
      for (int r = 0; r < 4; ++r) {
        oA[r] = (_Float16)(cA[r] + bb);
        oB[r] = (_Float16)(cB[r] + bb);
      }
      _Float16* vrow = vT16 + ((size_t)bh * HD_ + et * 16 + col) * S_ + s0 + w * 16 + quad * 4;
      *(half4*)(vrow) = oA;
      *(half4*)(vrow + 64) = oB;
    }
  }
}

// ---------------------------------------------------------------- flash attention, 2-wave blocks
// Same proven wave-level geometry as R4 (4 q-tiles/wave, swizzled K/V LDS,
// double-buffer, full-drain barrier), but block = 2 waves (128 q-rows) and
// grid = 1024. R4's 512-block grid capped the CU at 2 blocks (8 waves); now
// LDS caps at ~5 blocks/CU (10 waves) and barriers sync only 2 lockstep
// waves within independent blocks -> latency hiding across blocks.
// Cost: K/V staged 8x per bh instead of 4x (L2-served). XCD swizzle
// preserved: all qblk blocks of a bh are == bh (mod 8).
__global__ __launch_bounds__(128, 2) void attn_kernel(
    const _Float16* __restrict__ q, const _Float16* __restrict__ k,
    const _Float16* __restrict__ vT, const float* __restrict__ maskadd,
    _Float16* __restrict__ att) {
  __shared__ alignas(16) _Float16 Ks[2][64 * 64];
  __shared__ alignas(16) _Float16 Vs[2][64 * 64];
  const int bh = blockIdx.x & 127;
  const int qblk = blockIdx.x >> 7;  // 0..7
  const int b = bh >> 4, h = bh & 15;
  const int wv = threadIdx.x >> 6;   // 0..1
  const int lane = threadIdx.x & 63;
  const int quad = lane >> 4, col = lane & 15;
  const int c7 = col & 7;
  const int q0 = qblk * 128 + wv * 64;

  const _Float16* __restrict__ kb = k + (size_t)bh * S_ * HD_;
  const _Float16* __restrict__ vb = vT + (size_t)bh * HD_ * S_;
  const float* __restrict__ mrow = maskadd + b * S_;

  // staging: slot s = wv*256 + i*64 + lane (i=0..3) covers 512 slots x 16B;
  // row = s>>3, seg' = (s&7)^(row&7); LDS dest linear at s*16 (same map as R4).
  int offK[4], offV[4], ldsb[4];
#pragma unroll
  for (int i = 0; i < 4; ++i) {
    const int s = wv * 256 + i * 64 + lane;
    const int r = s >> 3;
    const int sg = (s & 7) ^ (r & 7);
    offK[i] = r * 128 + sg * 16;
    offV[i] = r * 2048 + sg * 16;
    ldsb[i] = (wv * 256 + i * 64) * 8;  // halves: slot base (lane*16B added by HW)
  }

  half8 Qf[4][2];
#pragma unroll
  for (int qt = 0; qt < 4; ++qt) {
    const _Float16* qrow = q + ((size_t)bh * S_ + q0 + qt * 16 + col) * HD_;
    Qf[qt][0] = *(const half8*)(qrow + quad * 8);
    Qf[qt][1] = *(const half8*)(qrow + 32 + quad * 8);
  }

  const f32x4 z4 = {0.f, 0.f, 0.f, 0.f};
  f32x4 O[4][4];
#pragma unroll
  for (int qt = 0; qt < 4; ++qt)
#pragma unroll
    for (int et = 0; et < 4; ++et) O[qt][et] = z4;
  float l[4] = {0.f, 0.f, 0.f, 0.f};

  {
    const char* kg = (const char*)kb;
    const char* vg = (const char*)vb;
#pragma unroll
    for (int i = 0; i < 4; ++i) {
      gld16(kg + offK[i], &Ks[0][ldsb[i]]);
      gld16(vg + offV[i], &Vs[0][ldsb[i]]);
    }
  }
  int cur = 0;
  for (int c = 0; c < 16; ++c) {
    __syncthreads();
    if (c < 15) {
      const char* kg = (const char*)kb + (size_t)(c + 1) * 8192;
      const char* vg = (const char*)vb + (size_t)(c + 1) * 128;
#pragma unroll
      for (int i = 0; i < 4; ++i) {
        gld16(kg + offK[i], &Ks[cur ^ 1][ldsb[i]]);
        gld16(vg + offV[i], &Vs[cur ^ 1][ldsb[i]]);
      }
    }
    const int kk0 = c * 64;
    const _Float16* Kb_ = &Ks[cur][0];
    const _Float16* Vb_ = &Vs[cur][0];
    f32x4 mkv[4];
#pragma unroll
    for (int kt = 0; kt < 4; ++kt) mkv[kt] = *(const f32x4*)(mrow + kk0 + kt * 16 + quad * 4);
    half8 Kf[4][2];
#pragma unroll
    for (int kt = 0; kt < 4; ++kt) {
      const int rb = (kt * 16 + col) * 64;
      Kf[kt][0] = *(const half8*)&Kb_[rb + ((quad) ^ c7) * 8];
      Kf[kt][1] = *(const half8*)&Kb_[rb + ((4 + quad) ^ c7) * 8];
    }
    half4 Vf[4][4];
#pragma unroll
    for (int kt = 0; kt < 4; ++kt) {
      const int sb = ((kt * 2 + (quad >> 1)) ^ c7) * 8 + (quad & 1) * 4;
#pragma unroll
      for (int et = 0; et < 4; ++et) Vf[kt][et] = *(const half4*)&Vb_[(et * 16 + col) * 64 + sb];
    }
#pragma unroll
    for (int qt = 0; qt < 4; ++qt) {
      f32x4 st[4];
#pragma unroll
      for (int kt = 0; kt < 4; ++kt) {
        f32x4 s = __builtin_amdgcn_mfma_f32_16x16x32_f16(Kf[kt][0], Qf[qt][0], mkv[kt], 0, 0, 0);
        st[kt] = __builtin_amdgcn_mfma_f32_16x16x32_f16(Kf[kt][1], Qf[qt][1], s, 0, 0, 0);
      }
      float p[16];
#pragma unroll
      for (int kt = 0; kt < 4; ++kt)
#pragma unroll
        for (int r = 0; r < 4; ++r) p[kt * 4 + r] = __builtin_amdgcn_exp2f(st[kt][r]);
      float s01 = (p[0] + p[1]) + (p[2] + p[3]);
      float s23 = (p[4] + p[5]) + (p[6] + p[7]);
      float s45 = (p[8] + p[9]) + (p[10] + p[11]);
      float s67 = (p[12] + p[13]) + (p[14] + p[15]);
      l[qt] += (s01 + s23) + (s45 + s67);
      half4 ph[4];
#pragma unroll
      for (int kt = 0; kt < 4; ++kt)
#pragma unroll
        for (int r = 0; r < 4; ++r) ph[kt][r] = (_Float16)p[kt * 4 + r];
#pragma unroll
      for (int et = 0; et < 4; ++et) {
        f32x4 o = O[qt][et];
#pragma unroll
        for (int kt = 0; kt < 4; ++kt)
          o = __builtin_amdgcn_mfma_f32_16x16x16f16(Vf[kt][et], ph[kt], o, 0, 0, 0);
        O[qt][et] = o;
      }
    }
    cur ^= 1;
  }
#pragma unroll
  for (int qt = 0; qt < 4; ++qt) {
    float lt = l[qt];
    lt += __shfl_xor(lt, 16);
    lt += __shfl_xor(lt, 32);
    const float inv = 1.0f / lt;
    _Float16* orow = att + ((size_t)(b * S_ + q0 + qt * 16 + col)) * D_ + h * HD_;
#pragma unroll
    for (int et = 0; et < 4; ++et) {
      half4 o;
#pragma unroll
      for (int r = 0; r < 4; ++r) o[r] = (_Float16)(O[qt][et][r] * inv);
      *(half4*)(orow + et * 16 + quad * 4) = o;
    }
  }
}

// ---------------------------------------------------------------- out projection, m97-style (R4 unchanged)
__global__ __launch_bounds__(256, 4) void outproj_kernel(
    const _Float16* __restrict__ A, const _Float16* __restrict__ Bw,
    const float* __restrict__ bo, float* __restrict__ C) {
  __shared__ alignas(16) _Float16 As[128 * 64];
  __shared__ alignas(16) _Float16 Bs[128 * 64];
  const int x_ = blockIdx.x & 7;
  const int t_ = blockIdx.x >> 3;
  const int n_ = t_ & 7;
  const int mlo = t_ >> 3;
  const int m0 = (x_ * 8 + mlo) * 128;
  const int n0 = n_ * 128;
  const int t = threadIdx.x;
  const int lane = t & 63, wv = t >> 6;
  const int quad = lane >> 4, col = lane & 15;
  const int mw = (wv >> 1) * 64, nw = (wv & 1) * 64;

  int rowS[4], segS[4];
#pragma unroll
  for (int sweep = 0; sweep < 4; ++sweep) {
    const int s = sweep * 256 + wv * 64 + lane;
    rowS[sweep] = s >> 3;
    segS[sweep] = (s & 7) ^ (rowS[sweep] & 7);
  }

  f32x4 acc[16];
  const f32x4 z4 = {0.f, 0.f, 0.f, 0.f};
#pragma unroll
  for (int i = 0; i < 16; ++i) acc[i] = z4;

  for (int kt = 0; kt < 16; ++kt) {
#pragma unroll
    for (int sweep = 0; sweep < 4; ++sweep) {
      const int ldsbase = (sweep * 256 + wv * 64) * 8;
      gld16(A + (size_t)(m0 + rowS[sweep]) * D_ + kt * 64 + segS[sweep] * 8, &As[ldsbase]);
      gld16(Bw + (size_t)(n0 + rowS[sweep]) * D_ + kt * 64 + segS[sweep] * 8, &Bs[ldsbase]);
    }
    __syncthreads();
#pragma unroll
    for (int ks = 0; ks < 2; ++ks) {
      half8 aF[4], bF[4];
#pragma unroll
      for (int mt = 0; mt < 4; ++mt) {
        const int row = mw + mt * 16 + col;
        aF[mt] = *(const half8*)&As[row * 64 + (((ks * 4 + quad) ^ (row & 7)) * 8)];
      }
#pragma unroll
      for (int nt = 0; nt < 4; ++nt) {
        const int row = nw + nt * 16 + col;
        bF[nt] = *(const half8*)&Bs[row * 64 + (((ks * 4 + quad) ^ (row & 7)) * 8)];
      }
#pragma unroll
      for (int mt = 0; mt < 4; ++mt)
#pragma unroll
        for (int nt = 0; nt < 4; ++nt)
          acc[mt * 4 + nt] =
              __builtin_amdgcn_mfma_f32_16x16x32_f16(aF[mt], bF[nt], acc[mt * 4 + nt], 0, 0, 0);
    }
    __syncthreads();
  }
#pragma unroll
  for (int mt = 0; mt < 4; ++mt)
#pragma unroll
    for (int nt = 0; nt < 4; ++nt) {
      f32x4 a = acc[mt * 4 + nt];
      const int n = n0 + nw + nt * 16 + col;
      const float bb = bo[n];
#pragma unroll
      for (int r = 0; r < 4; ++r) {
        const int mrow = m0 + mw + mt * 16 + quad * 4 + r;
        C[(size_t)mrow * D_ + n] = a[r] + bb;
      }
    }
}

// ---------------------------------------------------------------- launch
extern "C" void kernel_launch(void* const* d_in, const int* in_sizes, int n_in,
                              void* d_out, int out_size, void* d_ws, size_t ws_size,
                              hipStream_t stream) {
  const float* x  = (const float*)d_in[0];
  const float* Wq = (const float*)d_in[2];
  const float* bq = (const float*)d_in[3];
  const float* Wk = (const float*)d_in[4];
  const float* bk = (const float*)d_in[5];
  const float* Wv = (const float*)d_in[6];
  const float* bv = (const float*)d_in[7];
  const float* Wo = (const float*)d_in[8];
  const float* bo = (const float*)d_in[9];

  float* wsf     = (float*)d_ws;
  float* maskadd = wsf;                      // 8192 floats
  const size_t NE = (size_t)B_ * H_ * S_ * HD_;  // 8388608
  _Float16* hws  = (_Float16*)(wsf + 16384);
  _Float16* q16  = hws;
  _Float16* k16  = q16 + NE;
  _Float16* vT16 = k16 + NE;
  _Float16* att16 = vT16 + NE;
  _Float16* Wo16 = att16 + NE;               // 1048576 halves
  _Float16* Wc   = Wo16 + 1048576;           // 196608 halves
  float*    bs   = (float*)(Wc + 196608);    // 3072 floats

  prep_kernel<<<4896, 256, 0, stream>>>(Wq, bq, Wk, bk, Wv, bv, Wo, d_in[1],
                                        Wc, bs, Wo16, maskadd);
  qkv_kernel<<<B_ * H_ * (S_ / 128), 256, 0, stream>>>(x, Wc, bs, q16, k16, vT16);
  attn_kernel<<<B_ * H_ * (S_ / 128), 128, 0, stream>>>(q16, k16, vT16, maskadd, att16);
  outproj_kernel<<<(B_ * S_ / 128) * (D_ / 128), 256, 0, stream>>>(att16, Wo16, bo, (float*)d_out);
}

// Round 10
// 184.702 us; speedup vs baseline: 1.6223x; 1.0298x over previous
//
#include <hip/hip_runtime.h>
#include <float.h>

#define B_ 8
#define S_ 1024
#define D_ 1024
#define H_ 16
#define HD_ 64

typedef __attribute__((ext_vector_type(8))) _Float16 half8;
typedef __attribute__((ext_vector_type(4))) _Float16 half4;
typedef __attribute__((ext_vector_type(2))) __fp16 fp16x2;
typedef __attribute__((ext_vector_type(4))) float f32x4;

typedef union {
  half8 h8;
  struct { half4 lo; half4 hi; } s4;
  fp16x2 h2[4];
} h8u;

__device__ __forceinline__ void gld16(const void* g, void* l) {
  __builtin_amdgcn_global_load_lds(
      (const __attribute__((address_space(1))) void*)g,
      (__attribute__((address_space(3))) void*)l, 16, 0, 0);
}

// ---------------------------------------------------------------- fused prep
// Grid: [0,768) cast_wqkv, [768,800) mask expand, [800,4896) cast_wo.
__global__ __launch_bounds__(256) void prep_kernel(
    const float* __restrict__ Wq, const float* __restrict__ bq,
    const float* __restrict__ Wk, const float* __restrict__ bk,
    const float* __restrict__ Wv, const float* __restrict__ bv,
    const float* __restrict__ Wo, const void* __restrict__ mraw,
    _Float16* __restrict__ Wc, float* __restrict__ bs,
    _Float16* __restrict__ Wo16, float* __restrict__ maskadd) {
  const int bid = blockIdx.x;
  const int tid = threadIdx.x;
  if (bid < 768) {
    const int idx = bid * 256 + tid;  // < 196608
    const int d = idx & 63;
    const int e = (idx >> 6) & 63;
    const int t2 = idx >> 12;
    const int m = t2 % 3, h = t2 / 3;
    const int src = h * 4096 + d * 64 + e;
    float v = (m == 0) ? Wq[src] * 0.18033688f : (m == 1) ? Wk[src] : Wv[src];
    Wc[idx] = (_Float16)v;
    if (idx < 3072) {
      const int mm = idx >> 10, he = idx & 1023;
      float vv = (mm == 0) ? bq[he] * 0.18033688f : (mm == 1) ? bk[he] : bv[he];
      bs[idx] = vv;
    }
  } else if (bid < 800) {
    __shared__ int bad;
    if (tid == 0) bad = 0;
    __syncthreads();
    const unsigned int* mw = (const unsigned int*)mraw;
    int my = 0;
    for (int j = tid; j < 2048; j += 256) my |= (mw[j] & ~1u) ? 1 : 0;
    if (my) atomicOr(&bad, 1);
    __syncthreads();
    const int i = (bid - 768) * 256 + tid;
    const int f = bad;  // 1 => byte layout
    const int v = f ? (int)((const unsigned char*)mraw)[i] : ((const int*)mraw)[i];
    maskadd[i] = (v != 0) ? -FLT_MAX : 0.0f;
  } else {
    const int i = (bid - 800) * 256 + tid;  // < 1048576
    Wo16[i] = (_Float16)Wo[i];
  }
}

// ---------------------------------------------------------------- QKV projection (R4-proven)
// 128 rows per block (2 row-tiles): weight fragments loaded once, used for
// both tiles. R6's row-coalesced variant regressed; this is the best measured.
__global__ __launch_bounds__(256) void qkv_kernel(
    const float* __restrict__ x, const _Float16* __restrict__ Wc,
    const float* __restrict__ bs,
    _Float16* __restrict__ q16, _Float16* __restrict__ k16, _Float16* __restrict__ vT16) {
  const int tp = blockIdx.x & 7;    // tile pair: rows s0..s0+127
  const int bh = blockIdx.x >> 3;
  const int b = bh >> 4, h = bh & 15;
  const int s0 = tp * 128;
  const int w = threadIdx.x >> 6, lane = threadIdx.x & 63;
  const int col = lane & 15, quad = lane >> 4;
  const int srowA = s0 + w * 16 + col;   // tile A row
  const int srowB = srowA + 64;          // tile B row

  half8 XA0, XA1, XB0, XB1;
  {
    const float* xrA = x + ((size_t)(b * S_) + srowA) * D_ + h * HD_;
    const float* xrB = x + ((size_t)(b * S_) + srowB) * D_ + h * HD_;
    f32x4 a0 = *(const f32x4*)(xrA + quad * 8);
    f32x4 a1 = *(const f32x4*)(xrA + quad * 8 + 4);
    f32x4 a2 = *(const f32x4*)(xrA + 32 + quad * 8);
    f32x4 a3 = *(const f32x4*)(xrA + 32 + quad * 8 + 4);
    f32x4 b0 = *(const f32x4*)(xrB + quad * 8);
    f32x4 b1 = *(const f32x4*)(xrB + quad * 8 + 4);
    f32x4 b2 = *(const f32x4*)(xrB + 32 + quad * 8);
    f32x4 b3 = *(const f32x4*)(xrB + 32 + quad * 8 + 4);
#pragma unroll
    for (int j = 0; j < 4; ++j) {
      XA0[j] = (_Float16)a0[j]; XA0[4 + j] = (_Float16)a1[j];
      XA1[j] = (_Float16)a2[j]; XA1[4 + j] = (_Float16)a3[j];
      XB0[j] = (_Float16)b0[j]; XB0[4 + j] = (_Float16)b1[j];
      XB1[j] = (_Float16)b2[j]; XB1[4 + j] = (_Float16)b3[j];
    }
  }

  const _Float16* wbase = Wc + (size_t)h * 3 * 4096;
  const f32x4 z4 = {0.f, 0.f, 0.f, 0.f};
#pragma unroll
  for (int mm = 0; mm < 2; ++mm) {
    _Float16* outp = mm ? k16 : q16;
    const _Float16* wm = wbase + mm * 4096;
#pragma unroll
    for (int et = 0; et < 4; ++et) {
      const _Float16* wr = wm + (et * 16 + col) * 64;
      half8 W0 = *(const half8*)(wr + quad * 8);
      half8 W1 = *(const half8*)(wr + 32 + quad * 8);
      f32x4 bb = *(const f32x4*)(bs + mm * 1024 + h * 64 + et * 16 + quad * 4);
      f32x4 cA = __builtin_amdgcn_mfma_f32_16x16x32_f16(W0, XA0, z4, 0, 0, 0);
      cA = __builtin_amdgcn_mfma_f32_16x16x32_f16(W1, XA1, cA, 0, 0, 0);
      f32x4 cB = __builtin_amdgcn_mfma_f32_16x16x32_f16(W0, XB0, z4, 0, 0, 0);
      cB = __builtin_amdgcn_mfma_f32_16x16x32_f16(W1, XB1, cB, 0, 0, 0);
      half4 oA, oB;
#pragma unroll
      for (int r = 0; r < 4; ++r) {
        oA[r] = (_Float16)(cA[r] + bb[r]);
        oB[r] = (_Float16)(cB[r] + bb[r]);
      }
      *(half4*)(outp + ((size_t)bh * S_ + srowA) * HD_ + et * 16 + quad * 4) = oA;
      *(half4*)(outp + ((size_t)bh * S_ + srowB) * HD_ + et * 16 + quad * 4) = oB;
    }
  }
  {
    const _Float16* wm = wbase + 2 * 4096;
#pragma unroll
    for (int et = 0; et < 4; ++et) {
      const _Float16* wr = wm + (et * 16 + col) * 64;
      half8 W0 = *(const half8*)(wr + quad * 8);
      half8 W1 = *(const half8*)(wr + 32 + quad * 8);
      float bb = bs[2048 + h * 64 + et * 16 + col];
      f32x4 cA = __builtin_amdgcn_mfma_f32_16x16x32_f16(XA0, W0, z4, 0, 0, 0);
      cA = __builtin_amdgcn_mfma_f32_16x16x32_f16(XA1, W1, cA, 0, 0, 0);
      f32x4 cB = __builtin_amdgcn_mfma_f32_16x16x32_f16(XB0, W0, z4, 0, 0, 0);
      cB = __builtin_amdgcn_mfma_f32_16x16x32_f16(XB1, W1, cB, 0, 0, 0);
      half4 oA, oB;
#pragma unroll
      for (int r = 0; r < 4; ++r) {
        oA[r] = (_Float16)(cA[r] + bb);
        oB[r] = (_Float16)(cB[r] + bb);
      }
      _Float16* vrow = vT16 + ((size_t)bh * HD_ + et * 16 + col) * S_ + s0 + w * 16 + quad * 4;
      *(half4*)(vrow) = oA;
      *(half4*)(vrow + 64) = oB;
    }
  }
}

// ---------------------------------------------------------------- flash attention (R4 structure)
// R4's proven 4-wave/4-qt geometry, with two issue-count reductions on the
// per-chunk dependent chain (R8 showed the wall is chain-issue-bound, not
// occupancy/prefetch): (a) PV fused 16x16x16 -> 16x16x32 (R2-verified slot
// algebra; PV MFMA slots 64->32 per wave-chunk), operands assembled via
// union (no element-copy movs); (b) packed v_cvt_pkrtz_f16_f32 (cvt ops
// 64->32). exp2-domain p in [0,1] -> rtz rounding harmless.
__global__ __launch_bounds__(256, 2) void attn_kernel(
    const _Float16* __restrict__ q, const _Float16* __restrict__ k,
    const _Float16* __restrict__ vT, const float* __restrict__ maskadd,
    _Float16* __restrict__ att) {
  __shared__ alignas(16) _Float16 Ks[2][64 * 64];
  __shared__ alignas(16) _Float16 Vs[2][64 * 64];
  const int bh = blockIdx.x & 127;   // XCD swizzle: 4 q-blocks of a bh share XCD
  const int qblk = blockIdx.x >> 7;  // 0..3
  const int b = bh >> 4, h = bh & 15;
  const int wv = threadIdx.x >> 6;
  const int lane = threadIdx.x & 63;
  const int quad = lane >> 4, col = lane & 15;
  const int c7 = col & 7;
  const int q0 = qblk * 256 + wv * 64;

  const _Float16* __restrict__ kb = k + (size_t)bh * S_ * HD_;
  const _Float16* __restrict__ vb = vT + (size_t)bh * HD_ * S_;
  const float* __restrict__ mrow = maskadd + b * S_;

  const int jj0 = wv * 128 + lane, jj1 = jj0 + 64;
  const int r0s = jj0 >> 3, r1s = jj1 >> 3;
  const int sg0 = (jj0 & 7) ^ (r0s & 7), sg1 = (jj1 & 7) ^ (r1s & 7);
  const int offK0 = r0s * 128 + sg0 * 16, offK1 = r1s * 128 + sg1 * 16;
  const int offV0 = r0s * 2048 + sg0 * 16, offV1 = r1s * 2048 + sg1 * 16;
  const int ldsb0 = wv * 1024, ldsb1 = wv * 1024 + 512;

  half8 Qf[4][2];
#pragma unroll
  for (int qt = 0; qt < 4; ++qt) {
    const _Float16* qrow = q + ((size_t)bh * S_ + q0 + qt * 16 + col) * HD_;
    Qf[qt][0] = *(const half8*)(qrow + quad * 8);
    Qf[qt][1] = *(const half8*)(qrow + 32 + quad * 8);
  }

  const f32x4 z4 = {0.f, 0.f, 0.f, 0.f};
  f32x4 O[4][4];
#pragma unroll
  for (int qt = 0; qt < 4; ++qt)
#pragma unroll
    for (int et = 0; et < 4; ++et) O[qt][et] = z4;
  float l[4] = {0.f, 0.f, 0.f, 0.f};

  {
    const char* kg = (const char*)kb;
    const char* vg = (const char*)vb;
    gld16(kg + offK0, &Ks[0][ldsb0]);
    gld16(kg + offK1, &Ks[0][ldsb1]);
    gld16(vg + offV0, &Vs[0][ldsb0]);
    gld16(vg + offV1, &Vs[0][ldsb1]);
  }
  int cur = 0;
  for (int c = 0; c < 16; ++c) {
    __syncthreads();
    if (c < 15) {
      const char* kg = (const char*)kb + (size_t)(c + 1) * 8192;
      const char* vg = (const char*)vb + (size_t)(c + 1) * 128;
      gld16(kg + offK0, &Ks[cur ^ 1][ldsb0]);
      gld16(kg + offK1, &Ks[cur ^ 1][ldsb1]);
      gld16(vg + offV0, &Vs[cur ^ 1][ldsb0]);
      gld16(vg + offV1, &Vs[cur ^ 1][ldsb1]);
    }
    const int kk0 = c * 64;
    const _Float16* Kb_ = &Ks[cur][0];
    const _Float16* Vb_ = &Vs[cur][0];
    f32x4 mkv[4];
#pragma unroll
    for (int kt = 0; kt < 4; ++kt) mkv[kt] = *(const f32x4*)(mrow + kk0 + kt * 16 + quad * 4);
    half8 Kf[4][2];
#pragma unroll
    for (int kt = 0; kt < 4; ++kt) {
      const int rb = (kt * 16 + col) * 64;
      Kf[kt][0] = *(const half8*)&Kb_[rb + ((quad) ^ c7) * 8];
      Kf[kt][1] = *(const half8*)&Kb_[rb + ((4 + quad) ^ c7) * 8];
    }
    // fused V fragments: pair kt (0,1) and (2,3) -> half8 A-operands (R2 algebra)
    h8u Vf8[2][4];
#pragma unroll
    for (int pr = 0; pr < 2; ++pr) {
      const int sb0 = ((pr * 4 + (quad >> 1)) ^ c7) * 8 + (quad & 1) * 4;
      const int sb1 = ((pr * 4 + 2 + (quad >> 1)) ^ c7) * 8 + (quad & 1) * 4;
#pragma unroll
      for (int et = 0; et < 4; ++et) {
        const int rb = (et * 16 + col) * 64;
        Vf8[pr][et].s4.lo = *(const half4*)&Vb_[rb + sb0];
        Vf8[pr][et].s4.hi = *(const half4*)&Vb_[rb + sb1];
      }
    }
#pragma unroll
    for (int qt = 0; qt < 4; ++qt) {
      f32x4 st[4];
#pragma unroll
      for (int kt = 0; kt < 4; ++kt) {
        f32x4 s = __builtin_amdgcn_mfma_f32_16x16x32_f16(Kf[kt][0], Qf[qt][0], mkv[kt], 0, 0, 0);
        st[kt] = __builtin_amdgcn_mfma_f32_16x16x32_f16(Kf[kt][1], Qf[qt][1], s, 0, 0, 0);
      }
      float p[16];
#pragma unroll
      for (int kt = 0; kt < 4; ++kt)
#pragma unroll
        for (int r = 0; r < 4; ++r) p[kt * 4 + r] = __builtin_amdgcn_exp2f(st[kt][r]);
      float s01 = (p[0] + p[1]) + (p[2] + p[3]);
      float s23 = (p[4] + p[5]) + (p[6] + p[7]);
      float s45 = (p[8] + p[9]) + (p[10] + p[11]);
      float s67 = (p[12] + p[13]) + (p[14] + p[15]);
      l[qt] += (s01 + s23) + (s45 + s67);
      h8u pp0, pp1;
      pp0.h2[0] = __builtin_amdgcn_cvt_pkrtz(p[0], p[1]);
      pp0.h2[1] = __builtin_amdgcn_cvt_pkrtz(p[2], p[3]);
      pp0.h2[2] = __builtin_amdgcn_cvt_pkrtz(p[4], p[5]);
      pp0.h2[3] = __builtin_amdgcn_cvt_pkrtz(p[6], p[7]);
      pp1.h2[0] = __builtin_amdgcn_cvt_pkrtz(p[8], p[9]);
      pp1.h2[1] = __builtin_amdgcn_cvt_pkrtz(p[10], p[11]);
      pp1.h2[2] = __builtin_amdgcn_cvt_pkrtz(p[12], p[13]);
      pp1.h2[3] = __builtin_amdgcn_cvt_pkrtz(p[14], p[15]);
#pragma unroll
      for (int et = 0; et < 4; ++et) {
        f32x4 o = O[qt][et];
        o = __builtin_amdgcn_mfma_f32_16x16x32_f16(Vf8[0][et].h8, pp0.h8, o, 0, 0, 0);
        o = __builtin_amdgcn_mfma_f32_16x16x32_f16(Vf8[1][et].h8, pp1.h8, o, 0, 0, 0);
        O[qt][et] = o;
      }
    }
    cur ^= 1;
  }
#pragma unroll
  for (int qt = 0; qt < 4; ++qt) {
    float lt = l[qt];
    lt += __shfl_xor(lt, 16);
    lt += __shfl_xor(lt, 32);
    const float inv = 1.0f / lt;
    _Float16* orow = att + ((size_t)(b * S_ + q0 + qt * 16 + col)) * D_ + h * HD_;
#pragma unroll
    for (int et = 0; et < 4; ++et) {
      half4 o;
#pragma unroll
      for (int r = 0; r < 4; ++r) o[r] = (_Float16)(O[qt][et][r] * inv);
      *(half4*)(orow + et * 16 + quad * 4) = o;
    }
  }
}

// ---------------------------------------------------------------- out projection, m97-style (R4 unchanged)
__global__ __launch_bounds__(256, 4) void outproj_kernel(
    const _Float16* __restrict__ A, const _Float16* __restrict__ Bw,
    const float* __restrict__ bo, float* __restrict__ C) {
  __shared__ alignas(16) _Float16 As[128 * 64];
  __shared__ alignas(16) _Float16 Bs[128 * 64];
  const int x_ = blockIdx.x & 7;
  const int t_ = blockIdx.x >> 3;
  const int n_ = t_ & 7;
  const int mlo = t_ >> 3;
  const int m0 = (x_ * 8 + mlo) * 128;
  const int n0 = n_ * 128;
  const int t = threadIdx.x;
  const int lane = t & 63, wv = t >> 6;
  const int quad = lane >> 4, col = lane & 15;
  const int mw = (wv >> 1) * 64, nw = (wv & 1) * 64;

  int rowS[4], segS[4];
#pragma unroll
  for (int sweep = 0; sweep < 4; ++sweep) {
    const int s = sweep * 256 + wv * 64 + lane;
    rowS[sweep] = s >> 3;
    segS[sweep] = (s & 7) ^ (rowS[sweep] & 7);
  }

  f32x4 acc[16];
  const f32x4 z4 = {0.f, 0.f, 0.f, 0.f};
#pragma unroll
  for (int i = 0; i < 16; ++i) acc[i] = z4;

  for (int kt = 0; kt < 16; ++kt) {
#pragma unroll
    for (int sweep = 0; sweep < 4; ++sweep) {
      const int ldsbase = (sweep * 256 + wv * 64) * 8;
      gld16(A + (size_t)(m0 + rowS[sweep]) * D_ + kt * 64 + segS[sweep] * 8, &As[ldsbase]);
      gld16(Bw + (size_t)(n0 + rowS[sweep]) * D_ + kt * 64 + segS[sweep] * 8, &Bs[ldsbase]);
    }
    __syncthreads();
#pragma unroll
    for (int ks = 0; ks < 2; ++ks) {
      half8 aF[4], bF[4];
#pragma unroll
      for (int mt = 0; mt < 4; ++mt) {
        const int row = mw + mt * 16 + col;
        aF[mt] = *(const half8*)&As[row * 64 + (((ks * 4 + quad) ^ (row & 7)) * 8)];
      }
#pragma unroll
      for (int nt = 0; nt < 4; ++nt) {
        const int row = nw + nt * 16 + col;
        bF[nt] = *(const half8*)&Bs[row * 64 + (((ks * 4 + quad) ^ (row & 7)) * 8)];
      }
#pragma unroll
      for (int mt = 0; mt < 4; ++mt)
#pragma unroll
        for (int nt = 0; nt < 4; ++nt)
          acc[mt * 4 + nt] =
              __builtin_amdgcn_mfma_f32_16x16x32_f16(aF[mt], bF[nt], acc[mt * 4 + nt], 0, 0, 0);
    }
    __syncthreads();
  }
#pragma unroll
  for (int mt = 0; mt < 4; ++mt)
#pragma unroll
    for (int nt = 0; nt < 4; ++nt) {
      f32x4 a = acc[mt * 4 + nt];
      const int n = n0 + nw + nt * 16 + col;
      const float bb = bo[n];
#pragma unroll
      for (int r = 0; r < 4; ++r) {
        const int mrow = m0 + mw + mt * 16 + quad * 4 + r;
        C[(size_t)mrow * D_ + n] = a[r] + bb;
      }
    }
}

// ---------------------------------------------------------------- launch
extern "C" void kernel_launch(void* const* d_in, const int* in_sizes, int n_in,
                              void* d_out, int out_size, void* d_ws, size_t ws_size,
                              hipStream_t stream) {
  const float* x  = (const float*)d_in[0];
  const float* Wq = (const float*)d_in[2];
  const float* bq = (const float*)d_in[3];
  const float* Wk = (const float*)d_in[4];
  const float* bk = (const float*)d_in[5];
  const float* Wv = (const float*)d_in[6];
  const float* bv = (const float*)d_in[7];
  const float* Wo = (const float*)d_in[8];
  const float* bo = (const float*)d_in[9];

  float* wsf     = (float*)d_ws;
  float* maskadd = wsf;                      // 8192 floats
  const size_t NE = (size_t)B_ * H_ * S_ * HD_;  // 8388608
  _Float16* hws  = (_Float16*)(wsf + 16384);
  _Float16* q16  = hws;
  _Float16* k16  = q16 + NE;
  _Float16* vT16 = k16 + NE;
  _Float16* att16 = vT16 + NE;
  _Float16* Wo16 = att16 + NE;               // 1048576 halves
  _Float16* Wc   = Wo16 + 1048576;           // 196608 halves
  float*    bs   = (float*)(Wc + 196608);    // 3072 floats

  prep_kernel<<<4896, 256, 0, stream>>>(Wq, bq, Wk, bk, Wv, bv, Wo, d_in[1],
                                        Wc, bs, Wo16, maskadd);
  qkv_kernel<<<B_ * H_ * (S_ / 128), 256, 0, stream>>>(x, Wc, bs, q16, k16, vT16);
  attn_kernel<<<B_ * H_ * (S_ / 256), 256, 0, stream>>>(q16, k16, vT16, maskadd, att16);
  outproj_kernel<<<(B_ * S_ / 128) * (D_ / 128), 256, 0, stream>>>(att16, Wo16, bo, (float*)d_out);
}